// Round 10
// baseline (221.013 us; speedup 1.0000x reference)
//
#include <hip/hip_runtime.h>
#include <hip/hip_cooperative_groups.h>
#include <math.h>

namespace cg = cooperative_groups;

#define D 64
#define DH 32

typedef __attribute__((ext_vector_type(8))) short bf16x8;   // MFMA A/B frag (4 VGPRs)
typedef __attribute__((ext_vector_type(4))) float f32x4;    // MFMA C/D frag

// fp32 -> bf16 RNE
static __device__ __forceinline__ unsigned short f2b(float f) {
    unsigned int u = __builtin_bit_cast(unsigned int, f);
    u += 0x7FFFu + ((u >> 16) & 1u);
    return (unsigned short)(u >> 16);
}
static __device__ __forceinline__ unsigned int pack_b2(float a, float b) {
    return (unsigned int)f2b(a) | ((unsigned int)f2b(b) << 16);
}
// A&S 7.1.26 erf (|err| < 1.5e-7): 1 rcp + 1 exp + ~10 fma, no branches
static __device__ __forceinline__ float gelu_fast(float v) {
    const float ax = fabsf(v) * 0.70710678118654752f;
    const float t  = __builtin_amdgcn_rcpf(fmaf(0.3275911f, ax, 1.0f));
    float poly = fmaf(1.061405429f, t, -1.453152027f);
    poly = fmaf(poly, t, 1.421413741f);
    poly = fmaf(poly, t, -0.284496736f);
    poly = fmaf(poly, t, 0.254829592f);
    poly *= t;
    float er = fmaf(-poly, __expf(-ax * ax), 1.0f);
    er = copysignf(er, v);
    return 0.5f * v * (1.0f + er);
}

// ---------------------------------------------------------------------------
// Softmax over each row-segment sums to exactly 1, so
//   out[i] = has_edge(i) ? h[i]*(1+peak[i]) + bias : bias
// ---------------------------------------------------------------------------

// ======================= fallback path (r9, proven) =========================
__global__ void edge_flag_kernel(const int* __restrict__ row,
                                 unsigned char* __restrict__ flag, int E) {
    int i4 = (blockIdx.x * blockDim.x + threadIdx.x) * 4;
    if (i4 + 3 < E) {
        int4 r = *(const int4*)(row + i4);
        flag[r.x] = 1; flag[r.y] = 1; flag[r.z] = 1; flag[r.w] = 1;
    } else if (i4 < E) {
        for (int j = i4; j < E; ++j) flag[row[j]] = 1;
    }
}

__global__ void prep_kernel(const float* __restrict__ Wlin, const float* __restrict__ W1,
                            const float* __restrict__ bias, const float* __restrict__ b1,
                            const float* __restrict__ W2,
                            uint4* __restrict__ flag4, int nflag4,
                            unsigned short* __restrict__ packAW,
                            unsigned short* __restrict__ packAW1, float* __restrict__ packBias,
                            float* __restrict__ packB1, float* __restrict__ packW2)
{
    const int idx = blockIdx.x * blockDim.x + threadIdx.x;
    const int stride = gridDim.x * blockDim.x;
    const uint4 z = {0u, 0u, 0u, 0u};
    for (int i = idx; i < nflag4; i += stride) flag4[i] = z;

    if (blockIdx.x == 0) {
        const int lane = threadIdx.x & 63, part = threadIdx.x >> 6;
        const int q = lane >> 4, m = lane & 15;
#pragma unroll
        for (int fo = 0; fo < 2; ++fo) {
            const int f = part * 2 + fo, nt = f >> 1, ks = f & 1;
#pragma unroll
            for (int j = 0; j < 8; ++j)
                packAW[(f * 64 + lane) * 8 + j] = f2b(Wlin[(32 * ks + 8 * q + j) * D + 16 * nt + m]);
        }
        {
            const int f = part, ntW = f >> 1, ks = f & 1;
#pragma unroll
            for (int j = 0; j < 8; ++j)
                packAW1[(f * 64 + lane) * 8 + j] = f2b(W1[(32 * ks + 8 * q + j) * DH + 16 * ntW + m]);
        }
#pragma unroll
        for (int r = 0; r < 4; ++r)
            packBias[(part * 64 + lane) * 4 + r] = bias[16 * part + 4 * q + r];
        if (part < 2) {
#pragma unroll
            for (int r = 0; r < 4; ++r)
                packB1[(part * 64 + lane) * 4 + r] = b1[16 * part + 4 * q + r];
        } else {
#pragma unroll
            for (int r = 0; r < 4; ++r)
                packW2[((part - 2) * 64 + lane) * 4 + r] = W2[16 * (part - 2) + 4 * q + r];
        }
    }
}

// shared phase-C body (persistent grid-stride over 64-node tiles)
static __device__ __forceinline__ void compute_tiles(
    const float* __restrict__ x, const unsigned char* __restrict__ flag,
    const bf16x8 aw[4][2], const bf16x8 aw1[2][2],
    const f32x4& b1v0, const f32x4& b1v1, const f32x4& w2v0, const f32x4& w2v1,
    const f32x4 biasv[4], float b2s,
    unsigned short (*sHw)[72],       // per-wave [16][72]
    float* __restrict__ out, int N, int ntiles,
    int t0, int tstep, int wv, int lane, int q, int m)
{
    int t = t0;
    if (t >= ntiles) return;

    float4 cu0, cu1, cu2, cu3; unsigned char cfl;
    {
        int g = t * 64 + wv * 16 + m; if (g > N - 1) g = N - 1;
        const float* px = x + (size_t)g * D + 8 * q;
        cu0 = *(const float4*)(px);      cu1 = *(const float4*)(px + 4);
        cu2 = *(const float4*)(px + 32); cu3 = *(const float4*)(px + 36);
        cfl = flag[g];
    }

    while (true) {
        const int tn = t + tstep;
        const bool more = tn < ntiles;
        float4 nu0, nu1, nu2, nu3; unsigned char nfl = 0;
        if (more) {
            int g = tn * 64 + wv * 16 + m; if (g > N - 1) g = N - 1;
            const float* px = x + (size_t)g * D + 8 * q;
            nu0 = *(const float4*)(px);      nu1 = *(const float4*)(px + 4);
            nu2 = *(const float4*)(px + 32); nu3 = *(const float4*)(px + 36);
            nfl = flag[g];
        }

        uint4 pk0, pk1;
        pk0.x = pack_b2(cu0.x, cu0.y); pk0.y = pack_b2(cu0.z, cu0.w);
        pk0.z = pack_b2(cu1.x, cu1.y); pk0.w = pack_b2(cu1.z, cu1.w);
        pk1.x = pack_b2(cu2.x, cu2.y); pk1.y = pack_b2(cu2.z, cu2.w);
        pk1.z = pack_b2(cu3.x, cu3.y); pk1.w = pack_b2(cu3.z, cu3.w);
        const bf16x8 bx0 = __builtin_bit_cast(bf16x8, pk0);
        const bf16x8 bx1 = __builtin_bit_cast(bf16x8, pk1);

        f32x4 accH[4];
#pragma unroll
        for (int nt = 0; nt < 4; ++nt) accH[nt] = (f32x4){0.f, 0.f, 0.f, 0.f};
#pragma unroll
        for (int nt = 0; nt < 4; ++nt)
            accH[nt] = __builtin_amdgcn_mfma_f32_16x16x32_bf16(aw[nt][0], bx0, accH[nt], 0, 0, 0);
#pragma unroll
        for (int nt = 0; nt < 4; ++nt)
            accH[nt] = __builtin_amdgcn_mfma_f32_16x16x32_bf16(aw[nt][1], bx1, accH[nt], 0, 0, 0);

        asm volatile("" ::: "memory");
#pragma unroll
        for (int nt = 0; nt < 4; ++nt) {
            uint2 pk;
            pk.x = pack_b2(accH[nt][0], accH[nt][1]);
            pk.y = pack_b2(accH[nt][2], accH[nt][3]);
            *(uint2*)&sHw[m][16 * nt + 4 * q] = pk;
        }
        asm volatile("" ::: "memory");
        const bf16x8 a20 = *(const bf16x8*)&sHw[m][8 * q];
        const bf16x8 a21 = *(const bf16x8*)&sHw[m][32 + 8 * q];

        f32x4 acc20 = b1v0, acc21 = b1v1;
        acc20 = __builtin_amdgcn_mfma_f32_16x16x32_bf16(aw1[0][0], a20, acc20, 0, 0, 0);
        acc20 = __builtin_amdgcn_mfma_f32_16x16x32_bf16(aw1[0][1], a21, acc20, 0, 0, 0);
        acc21 = __builtin_amdgcn_mfma_f32_16x16x32_bf16(aw1[1][0], a20, acc21, 0, 0, 0);
        acc21 = __builtin_amdgcn_mfma_f32_16x16x32_bf16(aw1[1][1], a21, acc21, 0, 0, 0);

        float pp = 0.f;
#pragma unroll
        for (int r = 0; r < 4; ++r) {
            pp = fmaf(gelu_fast(acc20[r]), w2v0[r], pp);
            pp = fmaf(gelu_fast(acc21[r]), w2v1[r], pp);
        }
        pp += __shfl_xor(pp, 16);
        pp += __shfl_xor(pp, 32);
        const float sg = __builtin_amdgcn_rcpf(1.f + __expf(-(pp + b2s)));
        const float scale = (cfl != 0) ? (1.f + sg) : 0.f;

        const int g = t * 64 + wv * 16 + m;
        if (g < N) {
            float* po = out + (size_t)g * D + 4 * q;
#pragma unroll
            for (int nt = 0; nt < 4; ++nt) {
                f32x4 o;
#pragma unroll
                for (int r = 0; r < 4; ++r)
                    o[r] = fmaf(accH[nt][r], scale, biasv[nt][r]);
                *(f32x4*)(po + 16 * nt) = o;
            }
        }

        if (!more) break;
        cu0 = nu0; cu1 = nu1; cu2 = nu2; cu3 = nu3; cfl = nfl;
        t = tn;
    }
}

__global__ __launch_bounds__(256) void gat_mfma5(
    const float* __restrict__ x, const unsigned char* __restrict__ flag,
    const unsigned short* __restrict__ packAW, const unsigned short* __restrict__ packAW1,
    const float* __restrict__ packBias, const float* __restrict__ packB1,
    const float* __restrict__ packW2, const float* __restrict__ b2,
    float* __restrict__ out, int N, int ntiles)
{
    __shared__ unsigned short sH[4][16][72];
    const int tid = threadIdx.x, wv = tid >> 6, lane = tid & 63;
    const int q = lane >> 4, m = lane & 15;

    bf16x8 aw[4][2], aw1[2][2];
#pragma unroll
    for (int nt = 0; nt < 4; ++nt)
#pragma unroll
        for (int ks = 0; ks < 2; ++ks)
            aw[nt][ks] = ((const bf16x8*)packAW)[(nt * 2 + ks) * 64 + lane];
#pragma unroll
    for (int nt = 0; nt < 2; ++nt)
#pragma unroll
        for (int ks = 0; ks < 2; ++ks)
            aw1[nt][ks] = ((const bf16x8*)packAW1)[(nt * 2 + ks) * 64 + lane];
    const f32x4 b1v0 = ((const f32x4*)packB1)[0 * 64 + lane];
    const f32x4 b1v1 = ((const f32x4*)packB1)[1 * 64 + lane];
    const f32x4 w2v0 = ((const f32x4*)packW2)[0 * 64 + lane];
    const f32x4 w2v1 = ((const f32x4*)packW2)[1 * 64 + lane];
    f32x4 biasv[4];
#pragma unroll
    for (int nt = 0; nt < 4; ++nt) biasv[nt] = ((const f32x4*)packBias)[nt * 64 + lane];

    compute_tiles(x, flag, aw, aw1, b1v0, b1v1, w2v0, w2v1, biasv, b2[0],
                  sH[wv], out, N, ntiles, blockIdx.x, gridDim.x, wv, lane, q, m);
}

// ======================= fused cooperative path =============================
__global__ __launch_bounds__(256) void gat_coop2(
    const float* __restrict__ x, const int* __restrict__ row,
    const float* __restrict__ Wlin, const float* __restrict__ bias,
    const float* __restrict__ W1, const float* __restrict__ b1,
    const float* __restrict__ W2, const float* __restrict__ b2,
    unsigned char* __restrict__ flag,
    unsigned short* __restrict__ packAW, unsigned short* __restrict__ packAW1,
    float* __restrict__ packBias, float* __restrict__ packB1,
    float* __restrict__ packW2,
    float* __restrict__ out, int N, int E, int ntiles)
{
    __shared__ unsigned short sH[4][16][72];
    const int tid  = threadIdx.x;
    const int gtid = blockIdx.x * blockDim.x + tid;
    const int nthr = gridDim.x * blockDim.x;
    const int wv = tid >> 6, lane = tid & 63;
    const int q = lane >> 4, m = lane & 15;

    // ---- Phase A: zero flags (grid-stride) + pack (spread over blocks 0..19)
    const int nflag4 = (N + 15) >> 4;
    const uint4 z = {0u, 0u, 0u, 0u};
    for (int i = gtid; i < nflag4; i += nthr) ((uint4*)flag)[i] = z;

    if (blockIdx.x < 20 && tid < 64) {
        const int f = blockIdx.x;
        if (f < 8) {
            const int nt = f >> 1, ks = f & 1;
#pragma unroll
            for (int j = 0; j < 8; ++j)
                packAW[(f * 64 + lane) * 8 + j] = f2b(Wlin[(32 * ks + 8 * q + j) * D + 16 * nt + m]);
        } else if (f < 12) {
            const int g = f - 8, ntW = g >> 1, ks = g & 1;
#pragma unroll
            for (int j = 0; j < 8; ++j)
                packAW1[(g * 64 + lane) * 8 + j] = f2b(W1[(32 * ks + 8 * q + j) * DH + 16 * ntW + m]);
        } else if (f < 16) {
            const int nt = f - 12;
#pragma unroll
            for (int r = 0; r < 4; ++r)
                packBias[(nt * 64 + lane) * 4 + r] = bias[16 * nt + 4 * q + r];
        } else if (f < 18) {
            const int c = f - 16;
#pragma unroll
            for (int r = 0; r < 4; ++r)
                packB1[(c * 64 + lane) * 4 + r] = b1[16 * c + 4 * q + r];
        } else {
            const int c = f - 18;
#pragma unroll
            for (int r = 0; r < 4; ++r)
                packW2[(c * 64 + lane) * 4 + r] = W2[16 * c + 4 * q + r];
        }
    }

    __threadfence();
    cg::this_grid().sync();

    // ---- Phase B: edge scatter (pack is readable now -> prefetch frags too)
    bf16x8 aw[4][2], aw1[2][2];
#pragma unroll
    for (int nt = 0; nt < 4; ++nt)
#pragma unroll
        for (int ks = 0; ks < 2; ++ks)
            aw[nt][ks] = ((const bf16x8*)packAW)[(nt * 2 + ks) * 64 + lane];
#pragma unroll
    for (int nt = 0; nt < 2; ++nt)
#pragma unroll
        for (int ks = 0; ks < 2; ++ks)
            aw1[nt][ks] = ((const bf16x8*)packAW1)[(nt * 2 + ks) * 64 + lane];
    const f32x4 b1v0 = ((const f32x4*)packB1)[0 * 64 + lane];
    const f32x4 b1v1 = ((const f32x4*)packB1)[1 * 64 + lane];
    const f32x4 w2v0 = ((const f32x4*)packW2)[0 * 64 + lane];
    const f32x4 w2v1 = ((const f32x4*)packW2)[1 * 64 + lane];
    f32x4 biasv[4];
#pragma unroll
    for (int nt = 0; nt < 4; ++nt) biasv[nt] = ((const f32x4*)packBias)[nt * 64 + lane];
    const float b2s = b2[0];

    for (int i4 = gtid * 4; i4 + 3 < E; i4 += nthr * 4) {
        const int4 r = *(const int4*)(row + i4);
        flag[r.x] = 1; flag[r.y] = 1; flag[r.z] = 1; flag[r.w] = 1;
    }
    if (gtid == 0) {
        for (int j = E & ~3; j < E; ++j) flag[row[j]] = 1;
    }

    __threadfence();
    cg::this_grid().sync();

    // ---- Phase C: persistent fused compute
    compute_tiles(x, flag, aw, aw1, b1v0, b1v1, w2v0, w2v1, biasv, b2s,
                  sH[wv], out, N, ntiles, blockIdx.x, gridDim.x, wv, lane, q, m);
}

extern "C" void kernel_launch(void* const* d_in, const int* in_sizes, int n_in,
                              void* d_out, int out_size, void* d_ws, size_t ws_size,
                              hipStream_t stream) {
    const float* x    = (const float*)d_in[0];
    const int*   eidx = (const int*)d_in[1];   // [2, E]: first E entries = row
    const float* Wlin = (const float*)d_in[2];
    // d_in[3] att_src, d_in[4] att_dst cancel (segment softmax sums to 1)
    const float* bias = (const float*)d_in[5];
    const float* W1   = (const float*)d_in[6];
    const float* b1   = (const float*)d_in[7];
    const float* W2   = (const float*)d_in[8];
    const float* b2   = (const float*)d_in[9];
    float* out = (float*)d_out;

    int N = in_sizes[0] / D;
    int E = in_sizes[1] / 2;

    char* ws = (char*)d_ws;
    unsigned char* flag = (unsigned char*)ws;
    const int nflag4 = (N + 15) / 16;
    const size_t off = (((size_t)nflag4 * 16) + 255) & ~(size_t)255;
    unsigned short* packAW   = (unsigned short*)(ws + off);            // 8192 B
    unsigned short* packAW1  = (unsigned short*)(ws + off + 8192);     // 4096 B
    float*          packBias = (float*)(ws + off + 12288);             // 4096 B
    float*          packB1   = (float*)(ws + off + 16384);             // 2048 B
    float*          packW2   = (float*)(ws + off + 18432);             // 2048 B

    int ntiles = (N + 63) / 64;
    int nblocks = 512; if (nblocks > ntiles) nblocks = ntiles;

    void* args[] = {
        (void*)&x, (void*)&eidx, (void*)&Wlin, (void*)&bias, (void*)&W1, (void*)&b1,
        (void*)&W2, (void*)&b2, (void*)&flag, (void*)&packAW, (void*)&packAW1,
        (void*)&packBias, (void*)&packB1, (void*)&packW2, (void*)&out,
        (void*)&N, (void*)&E, (void*)&ntiles
    };
    hipError_t err = hipLaunchCooperativeKernel((const void*)gat_coop2,
                                                dim3(nblocks), dim3(256), args, 0, stream);
    if (err != hipSuccess) {
        (void)hipGetLastError();   // clear sticky error, take proven 3-kernel path
        prep_kernel<<<256, 256, 0, stream>>>(Wlin, W1, bias, b1, W2,
                                             (uint4*)flag, nflag4,
                                             packAW, packAW1, packBias, packB1, packW2);
        edge_flag_kernel<<<(E / 4 + 255) / 256, 256, 0, stream>>>(eidx, flag, E);
        gat_mfma5<<<nblocks, 256, 0, stream>>>(x, flag, packAW, packAW1,
                                               packBias, packB1, packW2, b2, out, N, ntiles);
    }
}

// Round 11
// 32.432 us; speedup vs baseline: 6.8147x; 6.8147x over previous
//
#include <hip/hip_runtime.h>
#include <math.h>

#define D 64
#define DH 32

typedef __attribute__((ext_vector_type(8))) short bf16x8;   // MFMA A/B frag (4 VGPRs)
typedef __attribute__((ext_vector_type(4))) float f32x4;    // MFMA C/D frag

// fp32 -> bf16 RNE
static __device__ __forceinline__ unsigned short f2b(float f) {
    unsigned int u = __builtin_bit_cast(unsigned int, f);
    u += 0x7FFFu + ((u >> 16) & 1u);
    return (unsigned short)(u >> 16);
}
static __device__ __forceinline__ unsigned int pack_b2(float a, float b) {
    return (unsigned int)f2b(a) | ((unsigned int)f2b(b) << 16);
}
// A&S 7.1.26 erf (|err| < 1.5e-7): 1 rcp + 1 exp + ~10 fma, no branches
static __device__ __forceinline__ float gelu_fast(float v) {
    const float ax = fabsf(v) * 0.70710678118654752f;
    const float t  = __builtin_amdgcn_rcpf(fmaf(0.3275911f, ax, 1.0f));
    float poly = fmaf(1.061405429f, t, -1.453152027f);
    poly = fmaf(poly, t, 1.421413741f);
    poly = fmaf(poly, t, -0.284496736f);
    poly = fmaf(poly, t, 0.254829592f);
    poly *= t;
    float er = fmaf(-poly, __expf(-ax * ax), 1.0f);
    er = copysignf(er, v);
    return 0.5f * v * (1.0f + er);
}

// ---------------------------------------------------------------------------
// Softmax over each row-segment sums to exactly 1, so
//   out[i] = has_edge(i) ? h[i]*(1+peak[i]) + bias : bias
// att_src/att_dst/leaky-relu/segment-softmax cancel analytically.
// ---------------------------------------------------------------------------
__global__ void edge_flag_kernel(const int* __restrict__ row,
                                 unsigned char* __restrict__ flag, int E) {
    const int base = (blockIdx.x * blockDim.x + threadIdx.x) * 8;
    if (base + 7 < E) {
        const int4 a = *(const int4*)(row + base);
        const int4 b = *(const int4*)(row + base + 4);
        flag[a.x] = 1; flag[a.y] = 1; flag[a.z] = 1; flag[a.w] = 1;
        flag[b.x] = 1; flag[b.y] = 1; flag[b.z] = 1; flag[b.w] = 1;
    } else if (base < E) {
        for (int j = base; j < E; ++j) flag[row[j]] = 1;
    }
}

// ---------------------------------------------------------------------------
// Main: PERSISTENT grid-stride kernel (r9 structure, proven).  512 blocks x
// 4 waves; tile = 64 nodes (16/wave).  Prologue: each wave SELF-PACKS weight
// fragments from raw Wlin/W1/bias/b1/W2 (L2/L3-hot, 4-line coalesced gathers,
// ~112 independent dword loads) -- replaces the former prep dispatch.
// Hot loop: x-prefetch(next) || {cvt, 8+4 MFMA, wave-private LDS roundtrip,
// gelu-dot, epilogue store}.  No barriers anywhere.
// ---------------------------------------------------------------------------
__global__ __launch_bounds__(256) void gat_mfma6(
    const float* __restrict__ x, const unsigned char* __restrict__ flag,
    const float* __restrict__ Wlin, const float* __restrict__ bias,
    const float* __restrict__ W1, const float* __restrict__ b1,
    const float* __restrict__ W2, const float* __restrict__ b2,
    float* __restrict__ out, int N, int ntiles)
{
    __shared__ unsigned short sH[4][16][72];   // per-wave h bf16, 9 KB

    const int tid  = threadIdx.x;
    const int wv   = tid >> 6;
    const int lane = tid & 63;
    const int q    = lane >> 4;
    const int m    = lane & 15;

    // ---- prologue: self-pack weight fragments into registers ----
    bf16x8 aw[4][2], aw1[2][2];
#pragma unroll
    for (int nt = 0; nt < 4; ++nt)
#pragma unroll
        for (int ks = 0; ks < 2; ++ks) {
            bf16x8 a;
#pragma unroll
            for (int j = 0; j < 8; ++j)
                a[j] = (short)f2b(Wlin[(32 * ks + 8 * q + j) * D + 16 * nt + m]);
            aw[nt][ks] = a;
        }
#pragma unroll
    for (int nt = 0; nt < 2; ++nt)
#pragma unroll
        for (int ks = 0; ks < 2; ++ks) {
            bf16x8 a;
#pragma unroll
            for (int j = 0; j < 8; ++j)
                a[j] = (short)f2b(W1[(32 * ks + 8 * q + j) * DH + 16 * nt + m]);
            aw1[nt][ks] = a;
        }
    f32x4 b1v0, b1v1, w2v0, w2v1;
    f32x4 biasv[4];
#pragma unroll
    for (int r = 0; r < 4; ++r) {
        b1v0[r] = b1[4 * q + r];
        b1v1[r] = b1[16 + 4 * q + r];
        w2v0[r] = W2[4 * q + r];
        w2v1[r] = W2[16 + 4 * q + r];
#pragma unroll
        for (int nt = 0; nt < 4; ++nt)
            biasv[nt][r] = bias[16 * nt + 4 * q + r];
    }
    const float b2s = b2[0];

    int t = blockIdx.x;
    if (t >= ntiles) return;

    // ---- load tile t (cur) ----
    float4 cu0, cu1, cu2, cu3; unsigned char cfl;
    {
        int g = t * 64 + wv * 16 + m; if (g > N - 1) g = N - 1;
        const float* px = x + (size_t)g * D + 8 * q;
        cu0 = *(const float4*)(px);      cu1 = *(const float4*)(px + 4);
        cu2 = *(const float4*)(px + 32); cu3 = *(const float4*)(px + 36);
        cfl = flag[g];
    }

    while (true) {
        const int tn = t + gridDim.x;
        const bool more = tn < ntiles;
        // ---- prefetch tile tn (issued before compute; drains during MFMA) ----
        float4 nu0, nu1, nu2, nu3; unsigned char nfl = 0;
        if (more) {
            int g = tn * 64 + wv * 16 + m; if (g > N - 1) g = N - 1;
            const float* px = x + (size_t)g * D + 8 * q;
            nu0 = *(const float4*)(px);      nu1 = *(const float4*)(px + 4);
            nu2 = *(const float4*)(px + 32); nu3 = *(const float4*)(px + 36);
            nfl = flag[g];
        }

        // ---- cvt x -> bf16 B-frags ----
        uint4 pk0, pk1;
        pk0.x = pack_b2(cu0.x, cu0.y); pk0.y = pack_b2(cu0.z, cu0.w);
        pk0.z = pack_b2(cu1.x, cu1.y); pk0.w = pack_b2(cu1.z, cu1.w);
        pk1.x = pack_b2(cu2.x, cu2.y); pk1.y = pack_b2(cu2.z, cu2.w);
        pk1.z = pack_b2(cu3.x, cu3.y); pk1.w = pack_b2(cu3.z, cu3.w);
        const bf16x8 bx0 = __builtin_bit_cast(bf16x8, pk0);
        const bf16x8 bx1 = __builtin_bit_cast(bf16x8, pk1);

        // ---- GEMM1: h^T = W^T @ x^T ----
        f32x4 accH[4];
#pragma unroll
        for (int nt = 0; nt < 4; ++nt) accH[nt] = (f32x4){0.f, 0.f, 0.f, 0.f};
#pragma unroll
        for (int nt = 0; nt < 4; ++nt)
            accH[nt] = __builtin_amdgcn_mfma_f32_16x16x32_bf16(aw[nt][0], bx0, accH[nt], 0, 0, 0);
#pragma unroll
        for (int nt = 0; nt < 4; ++nt)
            accH[nt] = __builtin_amdgcn_mfma_f32_16x16x32_bf16(aw[nt][1], bx1, accH[nt], 0, 0, 0);
        // lane holds h[node = t*64+wv*16+m][hcol = 16nt+4q+r]

        // ---- h -> wave-private LDS roundtrip (bf16), relayout for GEMM2 ----
        asm volatile("" ::: "memory");
#pragma unroll
        for (int nt = 0; nt < 4; ++nt) {
            uint2 pk;
            pk.x = pack_b2(accH[nt][0], accH[nt][1]);
            pk.y = pack_b2(accH[nt][2], accH[nt][3]);
            *(uint2*)&sH[wv][m][16 * nt + 4 * q] = pk;
        }
        asm volatile("" ::: "memory");
        const bf16x8 a20 = *(const bf16x8*)&sH[wv][m][8 * q];
        const bf16x8 a21 = *(const bf16x8*)&sH[wv][m][32 + 8 * q];

        // ---- GEMM2: t^T = W1^T @ h^T ----
        f32x4 acc20 = b1v0, acc21 = b1v1;
        acc20 = __builtin_amdgcn_mfma_f32_16x16x32_bf16(aw1[0][0], a20, acc20, 0, 0, 0);
        acc20 = __builtin_amdgcn_mfma_f32_16x16x32_bf16(aw1[0][1], a21, acc20, 0, 0, 0);
        acc21 = __builtin_amdgcn_mfma_f32_16x16x32_bf16(aw1[1][0], a20, acc21, 0, 0, 0);
        acc21 = __builtin_amdgcn_mfma_f32_16x16x32_bf16(aw1[1][1], a21, acc21, 0, 0, 0);

        // ---- peak: pp = sum gelu(t)*W2; reduce over 4 q-groups ----
        float pp = 0.f;
#pragma unroll
        for (int r = 0; r < 4; ++r) {
            pp = fmaf(gelu_fast(acc20[r]), w2v0[r], pp);
            pp = fmaf(gelu_fast(acc21[r]), w2v1[r], pp);
        }
        pp += __shfl_xor(pp, 16);
        pp += __shfl_xor(pp, 32);
        const float sg = __builtin_amdgcn_rcpf(1.f + __expf(-(pp + b2s)));
        const float scale = (cfl != 0) ? (1.f + sg) : 0.f;

        // ---- epilogue: out = h*scale + bias ----
        const int g = t * 64 + wv * 16 + m;
        if (g < N) {
            float* po = out + (size_t)g * D + 4 * q;
#pragma unroll
            for (int nt = 0; nt < 4; ++nt) {
                f32x4 o;
#pragma unroll
                for (int r = 0; r < 4; ++r)
                    o[r] = fmaf(accH[nt][r], scale, biasv[nt][r]);
                *(f32x4*)(po + 16 * nt) = o;
            }
        }

        if (!more) break;
        cu0 = nu0; cu1 = nu1; cu2 = nu2; cu3 = nu3; cfl = nfl;
        t = tn;
    }
}

extern "C" void kernel_launch(void* const* d_in, const int* in_sizes, int n_in,
                              void* d_out, int out_size, void* d_ws, size_t ws_size,
                              hipStream_t stream) {
    const float* x    = (const float*)d_in[0];
    const int*   eidx = (const int*)d_in[1];   // [2, E]: first E entries = row
    const float* Wlin = (const float*)d_in[2];
    // d_in[3] att_src, d_in[4] att_dst cancel (segment softmax sums to 1)
    const float* bias = (const float*)d_in[5];
    const float* W1   = (const float*)d_in[6];
    const float* b1   = (const float*)d_in[7];
    const float* W2   = (const float*)d_in[8];
    const float* b2   = (const float*)d_in[9];
    float* out = (float*)d_out;

    const int N = in_sizes[0] / D;
    const int E = in_sizes[1] / 2;

    unsigned char* flag = (unsigned char*)d_ws;

    const int ntiles  = (N + 63) / 64;
    const int nblocks = (ntiles < 512) ? ntiles : 512;

    hipMemsetAsync(flag, 0, (size_t)N, stream);
    edge_flag_kernel<<<(E / 8 + 255) / 256, 256, 0, stream>>>(eidx, flag, E);
    gat_mfma6<<<nblocks, 256, 0, stream>>>(x, flag, Wlin, bias, W1, b1, W2, b2,
                                           out, N, ntiles);
}